// Round 6
// baseline (139.408 us; speedup 1.0000x reference)
//
#include <hip/hip_runtime.h>
#include <hip/hip_bf16.h>
#include <math.h>

// Problem constants (from reference)
#define NDIM   8
#define NBINS  64
#define LOG_BETA   (-13.815510557964274f)  // log(1e-6)
#define LN2F       0.69314718055994531f
// mesh geometric, ratio 1.2: bin from |x| via g = log2(1+ALPHA|x|)/log2(1.2)
#define ALPHA      34.0821892f
#define INV_LOG2R  3.80178401692393f       // 1/log2(1.2)
#define WMAX       341.821892f             // fma(ALPHA,10,1): |x|=10 boundary

// Two threads per point: lane g handles float4 half (g&1) of point (g>>1).
__global__ __launch_bounds__(256, 8) void cdfq_fused(const float* __restrict__ x,
                                                     const float* __restrict__ logdet_in,
                                                     const float* __restrict__ p,
                                                     float* __restrict__ y_out,
                                                     float* __restrict__ ld_out,
                                                     int n)
{
    __shared__ float  mesh[65];
    __shared__ float  elmt[64];
    __shared__ float  sc[NDIM];
    __shared__ float  pdfs[NDIM][65];      // [d][k] — bank-friendly (65 stride)
    __shared__ float4 stbl[NDIM * NBINS];  // [d][k]: {v1, slope, F_pre, mesh_k}

    const int t  = threadIdx.x;
    const int T  = gridDim.x * blockDim.x;         // work-item stride
    const int i0 = blockIdx.x * blockDim.x + t;
    const int G  = 2 * n;                          // half-point work items
    const int iters = G / T;                       // wave-uniform (8 here)
    const float4* xv4 = (const float4*)x;

    // ---- prologue: two iterations' loads in flight before prep ----
    float4 X0, X1; float L0, L1;
    if (iters > 1) {
        X0 = xv4[i0];           L0 = logdet_in[i0 >> 1];
        X1 = xv4[i0 + T];       L1 = logdet_in[(i0 + T) >> 1];
    }
    __builtin_amdgcn_sched_barrier(0);   // do not sink these below prep

    // ---- prep phase (identical to round 5 — proven) ----
    if (t < 65) {
        float fidx = (float)t - 32.0f;
        float a = fabsf(fidx);
        float x1L = 2.0f / (powf(1.2f, 32.0f) - 1.0f);
        float xr = x1L * (powf(1.2f, a) - 1.0f) / 0.2f;
        xr = (fidx >= 0.0f) ? xr : -xr;
        xr = (xr + 10.0f) / 20.0f;
        if (t == 0)  xr = 0.0f;
        if (t == 64) xr = 1.0f;
        mesh[t] = xr;
    }
    for (int idx = t; idx < 63 * NDIM; idx += 256) {
        int d = idx & 7, k = idx >> 3;
        pdfs[d][k + 1] = expf(p[k * NDIM + d]);
    }
    if (t < NDIM) { pdfs[t][0] = 1e-6f; pdfs[t][64] = 1e-6f; }
    __syncthreads();
    if (t < 64) elmt[t] = mesh[t + 1] - mesh[t];
    __syncthreads();
    if (t < 64) {
        for (int d = 0; d < NDIM; ++d) {
            float w = 0.0f;
            if (t < 63) w = pdfs[d][t + 1] * 0.5f * (elmt[t] + elmt[t + 1]);
            for (int off = 32; off > 0; off >>= 1) w += __shfl_down(w, off);
            if (t == 0) sc[d] = (1.0f - (elmt[0] + elmt[63]) * 5e-7f) / w;
        }
    }
    __syncthreads();
    for (int idx = t; idx < 63 * NDIM; idx += 256) {
        int d = idx & 7, k = idx >> 3;
        pdfs[d][k + 1] *= sc[d];
    }
    __syncthreads();
    if (t < 64) {
        for (int d = 0; d < NDIM; ++d) {
            float c0 = 0.5f * (pdfs[d][t] + pdfs[d][t + 1]) * elmt[t];
            float v = c0;
            for (int off = 1; off < 64; off <<= 1) {
                float w = __shfl_up(v, off);
                if (t >= off) v += w;
            }
            float Fpre = v - c0;
            float v1 = pdfs[d][t];
            float v2 = pdfs[d][t + 1];
            stbl[d * 64 + t] = make_float4(v1, (v2 - v1) / elmt[t], Fpre, mesh[t]);
        }
    }
    __syncthreads();

    // per-lane table base: dims 0-3 (even lanes) or 4-7 (odd lanes)
    const float4* tp = stbl + ((i0 & 1) << 8);     // (g&1)*4*64

    // ---- lean per-half-point body ----
    auto body = [&](float4 X, float Lin, int g) {
        float xd[4] = {X.x, X.y, X.z, X.w};
        float yd[4];
        float prod = 1.0f, extra = 0.0f;

#pragma unroll
        for (int dl = 0; dl < 4; ++dl) {
            float xo = xd[dl];
            float xs = fmaf(xo, 0.05f, 0.5f);               // (x+10)/20
            float w  = fmaf(ALPHA, fabsf(xo), 1.0f);        // abs folds into fma
            float gg = __log2f(w) * INV_LOG2R;
            int   jf = (int)fminf(gg, 31.0f);
            int   m  = ((int)__float_as_int(xo)) >> 31;     // 0 or -1 (sign)
            int   k  = 32 + (jf ^ m);                       // pos: 32+jf, neg: 31-jf
            bool cov = w < WMAX;                            // |x| < 10

            float4 tb = tp[(dl << 6) + k];                  // {v1, slope, F_pre, mesh_k}
            float xm  = xs - tb.w;
            float yc  = fmaf(xm, fmaf(0.5f * xm, tb.y, tb.x), tb.z);
            float dv  = fmaf(xm, tb.y, tb.x);
            float yy  = cov ? yc : xs;
            prod *= (cov ? dv : 1.0f);                      // >= 1e-24, no underflow

            yy = fmaf(yy, 20.0f, -10.0f);
            float ay = fabsf(yy);
            bool cl  = ay > 10.0f;
            float yl = copysignf(fmaf(1e-6f, ay, 10.0f - 1e-5f), yy); // b(ay-10)+10
            yy = cl ? yl : yy;
            extra += cl ? LOG_BETA : 0.0f;
            yd[dl] = yy;
        }

        // one log2 of the 4-way product (min 1e-24 >> FLT_MIN)
        float contrib = fmaf(__log2f(prod), LN2F, extra);
        float cross   = __shfl_xor(contrib, 1);             // partner half-point

        ((float4*)y_out)[g] = make_float4(yd[0], yd[1], yd[2], yd[3]);
        ld_out[g >> 1] = Lin + contrib + cross;             // both lanes write same value
    };

    // ---- main loop: 2 bodies/iter, 2-deep guard-free pipeline ----
    for (int j = 0; j + 1 < iters; j += 2) {
        float4 Xn0, Xn1; float Ln0, Ln1;
        const bool more = (j + 3 < iters);                  // wave-uniform
        if (more) {
            int g2 = i0 + (j + 2) * T;
            int g3 = i0 + (j + 3) * T;
            Xn0 = xv4[g2]; Ln0 = logdet_in[g2 >> 1];
            Xn1 = xv4[g3]; Ln1 = logdet_in[g3 >> 1];
        }
        __builtin_amdgcn_sched_barrier(0);                  // keep prefetch on top

        body(X0, L0, i0 + j * T);
        body(X1, L1, i0 + (j + 1) * T);

        if (more) { X0 = Xn0; L0 = Ln0; X1 = Xn1; L1 = Ln1; }
    }

    // ---- remainder (never runs when T*2 | G; kept for generality) ----
    for (int g = i0 + (iters & ~1) * T; g < G; g += T)
        body(xv4[g], logdet_in[g >> 1], g);
}

extern "C" void kernel_launch(void* const* d_in, const int* in_sizes, int n_in,
                              void* d_out, int out_size, void* d_ws, size_t ws_size,
                              hipStream_t stream) {
    const float* x      = (const float*)d_in[0];   // [N, 8]
    const float* logdet = (const float*)d_in[1];   // [N, 1]
    const float* p      = (const float*)d_in[2];   // [63, 8]

    const int n = in_sizes[1];                     // N points
    float* y_out  = (float*)d_out;                 // [N*8]
    float* ld_out = (float*)d_out + (size_t)n * NDIM;  // [N]

    const int block = 256;
    int grid = 2048;                               // 8 blocks/CU co-resident
    if ((long long)grid * block > 2LL * n) grid = (2 * n + block - 1) / block;
    cdfq_fused<<<grid, block, 0, stream>>>(x, logdet, p, y_out, ld_out, n);
}